// Round 7
// baseline (320.211 us; speedup 1.0000x reference)
//
#include <hip/hip_runtime.h>
#include <hip/hip_bf16.h>

// Problem constants (fixed by the reference setup)
constexpr int B  = 8;
constexpr int L  = 1024;
constexpr int S  = 512;
constexpr int VD = 64;    // velocity dim
constexpr int DM = 512;   // d_model == spatial_dim
constexpr int D3 = 192;   // 3 * VD
constexpr int H  = 8;     // heads
constexpr int DK = 64;    // dm / H

typedef __attribute__((ext_vector_type(8))) short s8v;     // 8 bf16 (4 VGPRs)
typedef __attribute__((ext_vector_type(4))) float f4v;     // MFMA accum

__device__ inline unsigned short f2b(float f) {            // f32 -> bf16 RNE
    unsigned int u = __builtin_bit_cast(unsigned int, f);
    u += 0x7fffu + ((u >> 16) & 1u);
    return (unsigned short)(u >> 16);
}
__device__ inline float b2f(unsigned int lo16) {           // bf16 bits -> f32
    return __builtin_bit_cast(float, lo16 << 16);
}

// async global->LDS, 16B per lane. LDS dest must be wave-uniform base +
// lane*16 (linear); swizzle is applied on the GLOBAL source side (rule 21).
__device__ __forceinline__ void gload16(const void* g, void* l) {
    __builtin_amdgcn_global_load_lds(
        (const __attribute__((address_space(1))) void*)g,
        (__attribute__((address_space(3))) void*)l, 16, 0, 0);
}

// ---------------------------------------------------------------------------
// Fused f32 -> bf16 cast for 7 buffers (scale folded for wq: 0.125*log2e)
// ---------------------------------------------------------------------------
struct CastArgs {
    const float* src[7];
    unsigned short* dst[7];
    int n[7];
    float scale[7];
};

__global__ __launch_bounds__(256) void cast7_k(CastArgs a) {
    int id = blockIdx.y;
    const float* s = a.src[id];
    unsigned short* d = a.dst[id];
    int n = a.n[id];
    float sc = a.scale[id];
    for (long i = (long)(blockIdx.x * 256 + threadIdx.x) * 4; i < n;
         i += (long)gridDim.x * 1024) {
        float4 f = *(const float4*)(s + i);
        ushort4 o;
        o.x = f2b(f.x * sc); o.y = f2b(f.y * sc);
        o.z = f2b(f.z * sc); o.w = f2b(f.w * sc);
        *(ushort4*)(d + i) = o;
    }
}

// ---------------------------------------------------------------------------
// Fused: build WkEff/WvEff[z][d][n] = sum_o wz[d,o] * Wpe[o, n=j*64+c]
// directly from f32 inputs. Wpe is the composed 9-tap conv weight
// (velocity -> x_pe fold). Grid ((9 j x 4 dq)+1 pad, 2 z), 256 thr.
// n in [576,640) zeroed (pad block) — also serves as the zero-source for
// convgemm's halo loads.
// ---------------------------------------------------------------------------
__global__ __launch_bounds__(256) void build_eff_k(
    const float* __restrict__ w3, const float* __restrict__ w5,
    const float* __restrict__ w7, const float* __restrict__ dw_w,
    const float* __restrict__ wk, const float* __restrict__ wv,
    unsigned short* __restrict__ WEff)        // 2x [DM, 640]
{
    int z = blockIdx.y;
    unsigned short* out = WEff + (long)z * DM * 640;
    int t = threadIdx.x;

    if (blockIdx.x == 36) {                   // zero pad n in [576, 640)
        for (int idx = t; idx < DM * 64; idx += 256) {
            int d = idx >> 6, c = idx & 63;
            out[(long)d * 640 + 576 + c] = 0;
        }
        return;
    }

    int j  = blockIdx.x >> 2;                 // 0..8
    int dq = blockIdx.x & 3;                  // 128-row d chunk
    int delta = j - 4;

    __shared__ float Wpe[192][64];            // 48 KB
    for (int e = t; e < 192 * 64; e += 256) {
        int o = e >> 6, c = e & 63;
        const float* w; int KW, P, oo;
        if (o < 64)       { w = w3; KW = 3; P = 1; oo = o; }
        else if (o < 128) { w = w5; KW = 5; P = 2; oo = o - 64; }
        else              { w = w7; KW = 7; P = 3; oo = o - 128; }
        float inv = 1.0f / S;
        float mu0 = dw_w[o * 3 + 0] * inv;
        float mu1 = 1.f + (dw_w[o * 3 + 1] - 1.f) * inv;
        float mu2 = dw_w[o * 3 + 2] * inv;
        float acc = 0.f;
        int k;
        k = delta + 1 + P; if (k >= 0 && k < KW) acc += mu0 * w[(oo * 64 + c) * KW + k];
        k = delta + P;     if (k >= 0 && k < KW) acc += mu1 * w[(oo * 64 + c) * KW + k];
        k = delta - 1 + P; if (k >= 0 && k < KW) acc += mu2 * w[(oo * 64 + c) * KW + k];
        Wpe[o][c] = acc;
    }
    __syncthreads();

    const float* wz = z ? wv : wk;
    int c = t & 63, q = t >> 6;               // q: wave id (uniform)
    for (int dd = 0; dd < 32; dd++) {
        int d = dq * 128 + q * 32 + dd;       // wave-uniform row
        float acc = 0.f;
        for (int o = 0; o < D3; o++)
            acc += wz[(long)d * D3 + o] * Wpe[o][c];
        out[(long)d * 640 + j * 64 + c] = f2b(acc);
    }
}

// ---------------------------------------------------------------------------
// C'(s,o): mean_rel (closed form) + all constant terms of the x_pe fold.
// ---------------------------------------------------------------------------
__global__ __launch_bounds__(192) void cprime_k(
    const float* __restrict__ rel_table, const float* __restrict__ b3,
    const float* __restrict__ b5, const float* __restrict__ b7,
    const float* __restrict__ dw_w, const float* __restrict__ dw_b,
    unsigned short* __restrict__ Cp)
{
    int j = blockIdx.x;          // s
    int d = threadIdx.x;         // o
    float acc = 0.f;
#pragma unroll
    for (int r = 1; r < 60; r++) {
        int i = j - (r - 30);
        if (i >= 0 && i < S) acc += rel_table[r * D3 + d];
    }
    float c60 = (float)max(0, j - 29);
    float c0  = (float)max(0, (S - 30) - j);
    acc += c60 * rel_table[60 * D3 + d] + c0 * rel_table[0 * D3 + d];
    float inv = 1.0f / S;
    float mean_rel = acc * inv;

    float bo  = (d < 64) ? b3[d] : (d < 128) ? b5[d - 64] : b7[d - 128];
    float dw0 = dw_w[d * 3], dw1 = dw_w[d * 3 + 1], dw2 = dw_w[d * 3 + 2];
    float r29 = rel_table[29 * D3 + d], r30 = rel_table[30 * D3 + d],
          r31 = rel_table[31 * D3 + d];
    float alpha = 1.f + (dw1 - 1.f) * inv, beta = dw0 * inv, gamma = dw2 * inv;

    float cp = mean_rel + bo * alpha + (dw1 * r30 + dw_b[d] - r30) * inv;
    if (j > 0)     cp += beta * bo + dw0 * r29 * inv;
    if (j < S - 1) cp += gamma * bo + dw2 * r31 * inv;
    Cp[j * D3 + d] = f2b(cp);
}

// ---------------------------------------------------------------------------
// bf16 MFMA GEMM (NT), z-batched. global_load_lds staging (16B/lane):
// linear LDS dest, column-swizzled global source.
// ---------------------------------------------------------------------------
template<bool BF16OUT>
__global__ __launch_bounds__(256) void gemm_bf16_nt(
    const unsigned short* __restrict__ A, const unsigned short* __restrict__ Bm,
    void* __restrict__ Cout, const float* __restrict__ bias,
    int M, int N, int K, int lda, int ldb, int ldc,
    long sAz, long sBz, long sCz)
{
    __shared__ __align__(16) unsigned short As[128 * 64];
    __shared__ __align__(16) unsigned short Bs[128 * 64];

    int z = blockIdx.z;
    A  += (long)z * sAz;
    Bm += (long)z * sBz;

    int t = threadIdx.x;
    int l = t & 63, w = t >> 6;
    int lx = l & 15, lh = l >> 4;
    int wr = w >> 1, wc = w & 1;
    int m0 = blockIdx.x * 128, n0 = blockIdx.y * 128;

    f4v acc[4][4] = {};

    for (int k0 = 0; k0 < K; k0 += 64) {
        __syncthreads();
#pragma unroll
        for (int p = 0; p < 4; p++) {
            int flat = p * 256 + t;
            int r = flat >> 3, c = flat & 7;
            int csw = (c ^ (r & 7)) * 8;
            gload16(A  + (long)(m0 + r) * lda + k0 + csw, As + flat * 8);
            gload16(Bm + (long)(n0 + r) * ldb + k0 + csw, Bs + flat * 8);
        }
        __syncthreads();
#pragma unroll
        for (int ks = 0; ks < 2; ks++) {
            s8v af[4], bf[4];
#pragma unroll
            for (int i = 0; i < 4; i++) {
                int ra = wr * 64 + i * 16 + lx;
                af[i] = *(const s8v*)(As + ra * 64 + (((ks * 4 + lh) ^ (ra & 7)) * 8));
                int rb = wc * 64 + i * 16 + lx;
                bf[i] = *(const s8v*)(Bs + rb * 64 + (((ks * 4 + lh) ^ (rb & 7)) * 8));
            }
#pragma unroll
            for (int i = 0; i < 4; i++)
#pragma unroll
                for (int j = 0; j < 4; j++)
                    acc[i][j] = __builtin_amdgcn_mfma_f32_16x16x32_bf16(
                        af[i], bf[j], acc[i][j], 0, 0, 0);
        }
    }

#pragma unroll
    for (int i = 0; i < 4; i++) {
#pragma unroll
        for (int r = 0; r < 4; r++) {
            int m = m0 + wr * 64 + i * 16 + lh * 4 + r;
#pragma unroll
            for (int j = 0; j < 4; j++) {
                int n = n0 + wc * 64 + j * 16 + lx;
                float v = acc[i][j][r];
                if (bias) v += bias[n];
                if (BF16OUT)
                    ((unsigned short*)Cout + (long)z * sCz)[(long)m * ldc + n] = f2b(v);
                else
                    ((float*)Cout + (long)z * sCz)[(long)m * ldc + n] = v;
            }
        }
    }
}

// ---------------------------------------------------------------------------
// K/V conv-GEMM, z-batched. gload_lds staging; halo rows redirect their
// global source to a 16B zero region (zsrc).
// ---------------------------------------------------------------------------
__global__ __launch_bounds__(256) void convgemm_k(
    const unsigned short* __restrict__ xvb,   // [B*S, 64] bf16
    const unsigned short* __restrict__ Weff0, // 2x [512, 640] bf16
    const float* __restrict__ bias0,          // 2x [512, 512] f32
    unsigned short* __restrict__ Cout0,       // 2x [B*S, 512] bf16
    const unsigned short* __restrict__ zsrc)  // >=16 zero bytes
{
    __shared__ __align__(16) unsigned short As[128 * 64];
    __shared__ __align__(16) unsigned short Bs[128 * 64];

    int z = blockIdx.z;
    const unsigned short* Weff = Weff0 + (long)z * DM * 640;
    const float* bias2d = bias0 + (long)z * S * DM;
    unsigned short* Cout = Cout0 + (long)z * B * S * DM;

    int t = threadIdx.x;
    int l = t & 63, w = t >> 6;
    int lx = l & 15, lh = l >> 4;
    int wr = w >> 1, wc = w & 1;
    int m0 = blockIdx.x * 128, n0 = blockIdx.y * 128;
    int b = m0 >> 9, s0 = m0 & 511;

    f4v acc[4][4] = {};

    for (int j = 0; j < 9; j++) {
        __syncthreads();
#pragma unroll
        for (int p = 0; p < 4; p++) {
            int flat = p * 256 + t;
            int r = flat >> 3, c = flat & 7;
            int csw = (c ^ (r & 7)) * 8;
            int ss = s0 + r + j - 4;
            const unsigned short* asrc = (ss >= 0 && ss < S)
                ? xvb + ((long)b * S + ss) * VD + csw : zsrc;
            gload16(asrc, As + flat * 8);
            gload16(Weff + (long)(n0 + r) * 640 + j * 64 + csw, Bs + flat * 8);
        }
        __syncthreads();
#pragma unroll
        for (int ks = 0; ks < 2; ks++) {
            s8v af[4], bf[4];
#pragma unroll
            for (int i = 0; i < 4; i++) {
                int ra = wr * 64 + i * 16 + lx;
                af[i] = *(const s8v*)(As + ra * 64 + (((ks * 4 + lh) ^ (ra & 7)) * 8));
                int rb = wc * 64 + i * 16 + lx;
                bf[i] = *(const s8v*)(Bs + rb * 64 + (((ks * 4 + lh) ^ (rb & 7)) * 8));
            }
#pragma unroll
            for (int i = 0; i < 4; i++)
#pragma unroll
                for (int jj = 0; jj < 4; jj++)
                    acc[i][jj] = __builtin_amdgcn_mfma_f32_16x16x32_bf16(
                        af[i], bf[jj], acc[i][jj], 0, 0, 0);
        }
    }

#pragma unroll
    for (int i = 0; i < 4; i++) {
#pragma unroll
        for (int r = 0; r < 4; r++) {
            int m = m0 + wr * 64 + i * 16 + lh * 4 + r;
            int s = m & 511;
#pragma unroll
            for (int jj = 0; jj < 4; jj++) {
                int n = n0 + wc * 64 + jj * 16 + lx;
                Cout[(long)m * DM + n] = f2b(acc[i][jj][r] + bias2d[(long)s * DM + n]);
            }
        }
    }
}

// ---------------------------------------------------------------------------
// MFMA flash attention, no-max softmax in base-2 (log2e folded into wq):
// p = 2^pacc = e^{qk/8} exactly; v_exp_f32 directly, no mul. K/V reg
// prefetch (T14); setprio around MFMA (T5).
// ---------------------------------------------------------------------------
__global__ __launch_bounds__(256) void attn_mfma_k(
    const unsigned short* __restrict__ qb, const unsigned short* __restrict__ kb,
    const unsigned short* __restrict__ vb, unsigned short* __restrict__ ob)
{
    __shared__ __align__(16) unsigned short Qs[64 * 64];
    __shared__ __align__(16) unsigned short Ks[64 * 64];
    __shared__ __align__(16) unsigned short Vt[64 * 64];
    __shared__ __align__(16) unsigned short Ps[64 * 64];

    int lt = blockIdx.x, h = blockIdx.y, b = blockIdx.z;
    int t = threadIdx.x, l = t & 63, w = t >> 6, lx = l & 15, lh = l >> 4;

    const unsigned short* qg = qb + ((long)(b * L + lt * 64)) * DM + h * 64;
    const unsigned short* kg = kb + ((long)b * S) * DM + h * 64;
    const unsigned short* vg = vb + ((long)b * S) * DM + h * 64;

    // stage Q
#pragma unroll
    for (int p = 0; p < 2; p++) {
        int flat = p * 256 + t;
        int r = flat >> 3, c = flat & 7;
        s8v v = *(const s8v*)(qg + (long)r * DM + c * 8);
        *(s8v*)(Qs + r * 64 + ((c ^ (r & 7)) * 8)) = v;
    }

    int kr0 = t >> 3, kc = t & 7;          // K staging coords
    int vs = t & 63, vdq = t >> 6;         // V staging coords
    s8v k0, k1, v0, v1;

    auto loadKV = [&](int st) {
        k0 = *(const s8v*)(kg + (long)(st * 64 + kr0) * DM + kc * 8);
        k1 = *(const s8v*)(kg + (long)(st * 64 + 32 + kr0) * DM + kc * 8);
        const unsigned short* vp = vg + (long)(st * 64 + vs) * DM + vdq * 16;
        v0 = *(const s8v*)(vp);
        v1 = *(const s8v*)(vp + 8);
    };
    auto writeKV = [&]() {
        *(s8v*)(Ks + kr0 * 64 + ((kc ^ (kr0 & 7)) * 8)) = k0;
        int r2 = 32 + kr0;
        *(s8v*)(Ks + r2 * 64 + ((kc ^ (r2 & 7)) * 8)) = k1;
#pragma unroll
        for (int e = 0; e < 8; e++) {
            int d1 = vdq * 16 + e;
            Vt[d1 * 64 + (((vs >> 3) ^ (d1 & 7)) * 8) + (vs & 7)] =
                (unsigned short)v0[e];
            int d2 = vdq * 16 + 8 + e;
            Vt[d2 * 64 + (((vs >> 3) ^ (d2 & 7)) * 8) + (vs & 7)] =
                (unsigned short)v1[e];
        }
    };

    loadKV(0);
    writeKV();
    __syncthreads();

    float lrow[4] = {0.f, 0.f, 0.f, 0.f};
    f4v oacc[4] = {};

    for (int st = 0; st < S / 64; st++) {
        if (st < S / 64 - 1) loadKV(st + 1);          // prefetch next tile

        // P = Q K^T  (scale * log2e folded into Q)
        f4v pacc[4] = {};
        __builtin_amdgcn_s_setprio(1);
#pragma unroll
        for (int ks = 0; ks < 2; ks++) {
            int qr = w * 16 + lx;
            s8v a = *(const s8v*)(Qs + qr * 64 + (((ks * 4 + lh) ^ (qr & 7)) * 8));
#pragma unroll
            for (int jf = 0; jf < 4; jf++) {
                int kr = jf * 16 + lx;
                s8v bf = *(const s8v*)(Ks + kr * 64 + (((ks * 4 + lh) ^ (kr & 7)) * 8));
                pacc[jf] = __builtin_amdgcn_mfma_f32_16x16x32_bf16(a, bf, pacc[jf], 0, 0, 0);
            }
        }
        __builtin_amdgcn_s_setprio(0);

        // softmax-lite: p = 2^x (v_exp_f32), accumulate row sums, store bf16
#pragma unroll
        for (int r = 0; r < 4; r++) {
            int prow = w * 16 + lh * 4 + r;
#pragma unroll
            for (int jf = 0; jf < 4; jf++) {
                float pe = __builtin_amdgcn_exp2f(pacc[jf][r]);
                lrow[r] += pe;
                int col = jf * 16 + lx;
                Ps[prow * 64 + (((col >> 3) ^ (prow & 7)) * 8) + (col & 7)] = f2b(pe);
            }
        }
        asm volatile("s_waitcnt lgkmcnt(0)" ::: "memory");   // wave-local P vis

        // O += P V
        __builtin_amdgcn_s_setprio(1);
#pragma unroll
        for (int ks2 = 0; ks2 < 2; ks2++) {
            int pr = w * 16 + lx;
            s8v pa = *(const s8v*)(Ps + pr * 64 + (((ks2 * 4 + lh) ^ (pr & 7)) * 8));
#pragma unroll
            for (int df = 0; df < 4; df++) {
                int vr = df * 16 + lx;
                s8v vf = *(const s8v*)(Vt + vr * 64 + (((ks2 * 4 + lh) ^ (vr & 7)) * 8));
                oacc[df] = __builtin_amdgcn_mfma_f32_16x16x32_bf16(pa, vf, oacc[df], 0, 0, 0);
            }
        }
        __builtin_amdgcn_s_setprio(0);
        __syncthreads();                   // all waves done with Ks/Vt
        if (st < S / 64 - 1) {
            writeKV();                     // commit prefetched tile
            __syncthreads();
        }
    }

    // epilogue: one lane-reduce of l per row, then write O/l
    unsigned short* og = ob + ((long)(b * L + lt * 64 + w * 16)) * DM + h * 64;
#pragma unroll
    for (int r = 0; r < 4; r++) {
        float ls = lrow[r];
#pragma unroll
        for (int msk = 1; msk < 16; msk <<= 1) ls += __shfl_xor(ls, msk);
        float inv = 1.f / ls;
#pragma unroll
        for (int df = 0; df < 4; df++)
            og[(long)(lh * 4 + r) * DM + df * 16 + lx] = f2b(oacc[df][r] * inv);
    }
}

// ---------------------------------------------------------------------------
// Final fuse: out = LN( x_spatial + sigmoid(gamma) * fc_out ), bf16 inputs
// for fc_out and gamma logits. Each thread owns 2 consecutive channels.
// ---------------------------------------------------------------------------
__global__ __launch_bounds__(256) void final_k(
    const float* __restrict__ xs, const unsigned short* __restrict__ fcb,
    const unsigned short* __restrict__ gb,
    const float* __restrict__ ln_g, const float* __restrict__ ln_b,
    float* __restrict__ out)
{
    int bl = blockIdx.x;                 // b*L + l
    int b = bl >> 10, lq = bl & 1023;
    int t = threadIdx.x;
    int d0 = t * 2;
    const unsigned short* g = gb + ((long)b * S + (lq & 511)) * DM;

    __shared__ float red[2][4];

    float2 xv = *(const float2*)(xs + (long)bl * DM + d0);
    unsigned int fp = *(const unsigned int*)(fcb + (long)bl * DM + d0);
    unsigned int gp = *(const unsigned int*)(g + d0);

    float fo0 = b2f(fp & 0xffffu), fo1 = b2f(fp >> 16);
    float ga0 = 1.f / (1.f + __expf(-b2f(gp & 0xffffu)));
    float ga1 = 1.f / (1.f + __expf(-b2f(gp >> 16)));
    float r0 = xv.x + ga0 * fo0;
    float r1 = xv.y + ga1 * fo1;

    float sum = r0 + r1, sumsq = r0 * r0 + r1 * r1;
#pragma unroll
    for (int msk = 1; msk < 64; msk <<= 1) {
        sum   += __shfl_xor(sum, msk);
        sumsq += __shfl_xor(sumsq, msk);
    }
    int wave = t >> 6;
    if ((t & 63) == 0) { red[0][wave] = sum; red[1][wave] = sumsq; }
    __syncthreads();
    float tot   = red[0][0] + red[0][1] + red[0][2] + red[0][3];
    float totsq = red[1][0] + red[1][1] + red[1][2] + red[1][3];

    float mu  = tot * (1.0f / DM);
    float var = totsq * (1.0f / DM) - mu * mu;
    float inv = rsqrtf(var + 1e-5f);

    float2 lg = *(const float2*)(ln_g + d0);
    float2 lb = *(const float2*)(ln_b + d0);
    float2 o;
    o.x = (r0 - mu) * inv * lg.x + lb.x;
    o.y = (r1 - mu) * inv * lg.y + lb.y;
    *(float2*)(out + (long)bl * DM + d0) = o;
}

// ---------------------------------------------------------------------------
// Launch
// ---------------------------------------------------------------------------
extern "C" void kernel_launch(void* const* d_in, const int* in_sizes, int n_in,
                              void* d_out, int out_size, void* d_ws, size_t ws_size,
                              hipStream_t stream) {
    (void)in_sizes; (void)n_in; (void)out_size; (void)ws_size;

    const float* x_spatial  = (const float*)d_in[0];
    const float* x_velocity = (const float*)d_in[1];
    const float* w_gamma    = (const float*)d_in[2];
    const float* w3 = (const float*)d_in[3];
    const float* b3 = (const float*)d_in[4];
    const float* w5 = (const float*)d_in[5];
    const float* b5 = (const float*)d_in[6];
    const float* w7 = (const float*)d_in[7];
    const float* b7 = (const float*)d_in[8];
    const float* rel_table = (const float*)d_in[9];
    const float* dw_w = (const float*)d_in[10];
    const float* dw_b = (const float*)d_in[11];
    const float* wq   = (const float*)d_in[12];
    const float* wk   = (const float*)d_in[13];
    const float* wv   = (const float*)d_in[14];
    const float* fc_w = (const float*)d_in[15];
    const float* fc_b = (const float*)d_in[16];
    const float* ln_g = (const float*)d_in[17];
    const float* ln_b = (const float*)d_in[18];
    float* out = (float*)d_out;

    char* p = (char*)d_ws;
    auto alloc = [&](size_t bytes) {
        char* r = p;
        p += (bytes + 255) & ~(size_t)255;
        return r;
    };
    float* Ck           = (float*)alloc((size_t)S * DM * 4);          // contiguous
    float* Cv           = (float*)alloc((size_t)S * DM * 4);          //   with Ck
    unsigned short* gamma_bf = (unsigned short*)alloc((size_t)B * S * DM * 2);
    unsigned short* fcb      = (unsigned short*)alloc((size_t)B * L * DM * 2);
    unsigned short* xs_bf   = (unsigned short*)alloc((size_t)B * L * DM * 2);
    unsigned short* xv_bf   = (unsigned short*)alloc((size_t)B * S * VD * 2);
    unsigned short* qbuf    = (unsigned short*)alloc((size_t)B * L * DM * 2);
    unsigned short* kbuf    = (unsigned short*)alloc((size_t)B * S * DM * 2);  // contiguous
    unsigned short* vbuf    = (unsigned short*)alloc((size_t)B * S * DM * 2);  //   with kbuf
    unsigned short* attn_bf = (unsigned short*)alloc((size_t)B * L * DM * 2);
    unsigned short* wq_bf   = (unsigned short*)alloc((size_t)DM * DM * 2);
    unsigned short* wk_bf   = (unsigned short*)alloc((size_t)DM * D3 * 2);     // contiguous
    unsigned short* wv_bf   = (unsigned short*)alloc((size_t)DM * D3 * 2);     //   with wk_bf
    unsigned short* fcw_bf  = (unsigned short*)alloc((size_t)DM * DM * 2);
    unsigned short* wg_bf   = (unsigned short*)alloc((size_t)DM * VD * 2);
    unsigned short* Cp      = (unsigned short*)alloc((size_t)S * D3 * 2);
    unsigned short* WkEff   = (unsigned short*)alloc((size_t)DM * 640 * 2);    // contiguous
    unsigned short* WvEff   = (unsigned short*)alloc((size_t)DM * 640 * 2);    //   with WkEff

    // 0) cast to bf16 (wq scaled by 0.125 * log2(e) for base-2 softmax)
    CastArgs ca;
    ca.src[0] = x_spatial;  ca.dst[0] = xs_bf;  ca.n[0] = B * L * DM; ca.scale[0] = 1.f;
    ca.src[1] = x_velocity; ca.dst[1] = xv_bf;  ca.n[1] = B * S * VD; ca.scale[1] = 1.f;
    ca.src[2] = wq;         ca.dst[2] = wq_bf;  ca.n[2] = DM * DM;    ca.scale[2] = 0.125f * 1.44269504089f;
    ca.src[3] = wk;         ca.dst[3] = wk_bf;  ca.n[3] = DM * D3;    ca.scale[3] = 1.f;
    ca.src[4] = wv;         ca.dst[4] = wv_bf;  ca.n[4] = DM * D3;    ca.scale[4] = 1.f;
    ca.src[5] = fc_w;       ca.dst[5] = fcw_bf; ca.n[5] = DM * DM;    ca.scale[5] = 1.f;
    ca.src[6] = w_gamma;    ca.dst[6] = wg_bf;  ca.n[6] = DM * VD;    ca.scale[6] = 1.f;
    cast7_k<<<dim3(4096, 7), 256, 0, stream>>>(ca);

    // 1) composed-weight precomputes
    //    WkEff/WvEff built directly from f32 inputs (fused, 1 launch)
    build_eff_k<<<dim3(37, 2), 256, 0, stream>>>(
        w3, w5, w7, dw_w, wk, wv, WkEff);
    cprime_k<<<dim3(S), 192, 0, stream>>>(rel_table, b3, b5, b7, dw_w, dw_b, Cp);

    //    Ck/Cv = C' @ {wk,wv}^T  (z-batched)
    gemm_bf16_nt<false><<<dim3(4, 4, 2), 256, 0, stream>>>(
        Cp, wk_bf, Ck, nullptr, S, DM, D3, D3, D3, DM,
        0L, (long)DM * D3, (long)S * DM);

    // 2) gamma logits (bf16): [4096,512] = xv_bf @ wg_bf^T, K=64
    gemm_bf16_nt<true><<<dim3(32, 4), 256, 0, stream>>>(
        xv_bf, wg_bf, gamma_bf, nullptr, B * S, DM, VD, VD, VD, DM, 0L, 0L, 0L);

    // 3) Q (bf16, pre-scaled): [8192,512], K=512
    gemm_bf16_nt<true><<<dim3(64, 4), 256, 0, stream>>>(
        xs_bf, wq_bf, qbuf, nullptr, B * L, DM, DM, DM, DM, DM, 0L, 0L, 0L);

    // 4) K/V via composed conv-GEMM (z-batched, 9 x K64 chunks)
    convgemm_k<<<dim3(32, 4, 2), 256, 0, stream>>>(
        xv_bf, WkEff, Ck, kbuf, WkEff + 576 /* zero region */);

    // 5) attention (bf16 out)
    attn_mfma_k<<<dim3(L / 64, H, B), 256, 0, stream>>>(qbuf, kbuf, vbuf, attn_bf);

    // 6) fc (bf16 out + bias): [8192,512], K=512
    gemm_bf16_nt<true><<<dim3(64, 4), 256, 0, stream>>>(
        attn_bf, fcw_bf, fcb, fc_b, B * L, DM, DM, DM, DM, DM, 0L, 0L, 0L);

    // 7) gated residual + LayerNorm
    final_k<<<dim3(B * L), 256, 0, stream>>>(
        x_spatial, fcb, gamma_bf, ln_g, ln_b, out);
}

// Round 8
// 210.305 us; speedup vs baseline: 1.5226x; 1.5226x over previous
//
#include <hip/hip_runtime.h>
#include <hip/hip_bf16.h>

// Problem constants (fixed by the reference setup)
constexpr int B  = 8;
constexpr int L  = 1024;
constexpr int S  = 512;
constexpr int VD = 64;    // velocity dim
constexpr int DM = 512;   // d_model == spatial_dim
constexpr int D3 = 192;   // 3 * VD
constexpr int H  = 8;     // heads
constexpr int DK = 64;    // dm / H

typedef __attribute__((ext_vector_type(8))) short s8v;     // 8 bf16 (4 VGPRs)
typedef __attribute__((ext_vector_type(4))) float f4v;     // MFMA accum

__device__ inline unsigned short f2b(float f) {            // f32 -> bf16 RNE
    unsigned int u = __builtin_bit_cast(unsigned int, f);
    u += 0x7fffu + ((u >> 16) & 1u);
    return (unsigned short)(u >> 16);
}
__device__ inline float b2f(unsigned int lo16) {           // bf16 bits -> f32
    return __builtin_bit_cast(float, lo16 << 16);
}

// async global->LDS, 16B per lane. LDS dest must be wave-uniform base +
// lane*16 (linear); swizzle is applied on the GLOBAL source side (rule 21).
__device__ __forceinline__ void gload16(const void* g, void* l) {
    __builtin_amdgcn_global_load_lds(
        (const __attribute__((address_space(1))) void*)g,
        (__attribute__((address_space(3))) void*)l, 16, 0, 0);
}

// ---------------------------------------------------------------------------
// Fused f32 -> bf16 cast for 7 buffers (scale folded for wq: 0.125*log2e)
// ---------------------------------------------------------------------------
struct CastArgs {
    const float* src[7];
    unsigned short* dst[7];
    int n[7];
    float scale[7];
};

__global__ __launch_bounds__(256) void cast7_k(CastArgs a) {
    int id = blockIdx.y;
    const float* s = a.src[id];
    unsigned short* d = a.dst[id];
    int n = a.n[id];
    float sc = a.scale[id];
    for (long i = (long)(blockIdx.x * 256 + threadIdx.x) * 4; i < n;
         i += (long)gridDim.x * 1024) {
        float4 f = *(const float4*)(s + i);
        ushort4 o;
        o.x = f2b(f.x * sc); o.y = f2b(f.y * sc);
        o.z = f2b(f.z * sc); o.w = f2b(f.w * sc);
        *(ushort4*)(d + i) = o;
    }
}

// ---------------------------------------------------------------------------
// Merged precompute (192 threads):
//  blocks [0,640):  WpeT[n][o] = composed 9-tap conv weight (bf16), rows
//                   n>=576 zeroed.
//  blocks [640,1152): Cp[j][o] = mean_rel + constant terms of x_pe fold.
// ---------------------------------------------------------------------------
__global__ __launch_bounds__(192) void prep_k(
    const float* __restrict__ w3, const float* __restrict__ w5,
    const float* __restrict__ w7, const float* __restrict__ dw_w,
    const float* __restrict__ rel_table, const float* __restrict__ b3,
    const float* __restrict__ b5, const float* __restrict__ b7,
    const float* __restrict__ dw_b,
    unsigned short* __restrict__ WpeT, unsigned short* __restrict__ Cp)
{
    int o = threadIdx.x;                 // 0..191
    float inv = 1.0f / S;

    if (blockIdx.x < 640) {              // ---- WpeT part ----
        int n = blockIdx.x;
        if (n >= 576) { WpeT[n * D3 + o] = 0; return; }
        int j = n >> 6, c = n & 63, delta = j - 4;
        const float* w; int KW, P, oo;
        if (o < 64)       { w = w3; KW = 3; P = 1; oo = o; }
        else if (o < 128) { w = w5; KW = 5; P = 2; oo = o - 64; }
        else              { w = w7; KW = 7; P = 3; oo = o - 128; }
        float mu0 = dw_w[o * 3 + 0] * inv;
        float mu1 = 1.f + (dw_w[o * 3 + 1] - 1.f) * inv;
        float mu2 = dw_w[o * 3 + 2] * inv;
        float acc = 0.f;
        int k;
        k = delta + 1 + P; if (k >= 0 && k < KW) acc += mu0 * w[(oo * 64 + c) * KW + k];
        k = delta + P;     if (k >= 0 && k < KW) acc += mu1 * w[(oo * 64 + c) * KW + k];
        k = delta - 1 + P; if (k >= 0 && k < KW) acc += mu2 * w[(oo * 64 + c) * KW + k];
        WpeT[n * D3 + o] = f2b(acc);
        return;
    }

    // ---- C' part ----
    int j = blockIdx.x - 640;            // s
    float acc = 0.f;
#pragma unroll
    for (int r = 1; r < 60; r++) {
        int i = j - (r - 30);
        if (i >= 0 && i < S) acc += rel_table[r * D3 + o];
    }
    float c60 = (float)max(0, j - 29);
    float c0  = (float)max(0, (S - 30) - j);
    acc += c60 * rel_table[60 * D3 + o] + c0 * rel_table[0 * D3 + o];
    float mean_rel = acc * inv;

    float bo  = (o < 64) ? b3[o] : (o < 128) ? b5[o - 64] : b7[o - 128];
    float dw0 = dw_w[o * 3], dw1 = dw_w[o * 3 + 1], dw2 = dw_w[o * 3 + 2];
    float r29 = rel_table[29 * D3 + o], r30 = rel_table[30 * D3 + o],
          r31 = rel_table[31 * D3 + o];
    float alpha = 1.f + (dw1 - 1.f) * inv, beta = dw0 * inv, gamma = dw2 * inv;

    float cp = mean_rel + bo * alpha + (dw1 * r30 + dw_b[o] - r30) * inv;
    if (j > 0)     cp += beta * bo + dw0 * r29 * inv;
    if (j < S - 1) cp += gamma * bo + dw2 * r31 * inv;
    Cp[j * D3 + o] = f2b(cp);
}

// ---------------------------------------------------------------------------
// Unified precompute GEMM (all M=512, K=192, lda=ldb=192, bf16 out):
//  z=0: WkEff = wk_bf @ WpeT^T   [512,640]
//  z=1: WvEff = wv_bf @ WpeT^T   [512,640]
//  z=2: Ckb   = Cp    @ wk_bf^T  [512,512]
//  z=3: Cvb   = Cp    @ wv_bf^T  [512,512]
// Grid (4, 5, 4); z>=2 blocks with n0>=512 exit.
// ---------------------------------------------------------------------------
__global__ __launch_bounds__(256) void pre_gemm_k(
    const unsigned short* __restrict__ wk_bf,
    const unsigned short* __restrict__ wv_bf,
    const unsigned short* __restrict__ WpeT,
    const unsigned short* __restrict__ Cp,
    unsigned short* __restrict__ WEff,        // 2x [512, 640]
    unsigned short* __restrict__ Cb)          // 2x [512, 512]
{
    __shared__ __align__(16) unsigned short As[128 * 64];
    __shared__ __align__(16) unsigned short Bs[128 * 64];

    int z = blockIdx.z;
    const unsigned short* A;
    const unsigned short* Bm;
    unsigned short* C;
    int N, ldc;
    if (z < 2) { A = z ? wv_bf : wk_bf; Bm = WpeT; C = WEff + (long)z * DM * 640; N = 640; ldc = 640; }
    else       { A = Cp; Bm = (z == 2) ? wk_bf : wv_bf; C = Cb + (long)(z - 2) * S * DM; N = 512; ldc = 512; }

    int m0 = blockIdx.x * 128, n0 = blockIdx.y * 128;
    if (n0 >= N) return;

    int t = threadIdx.x;
    int l = t & 63, w = t >> 6;
    int lx = l & 15, lh = l >> 4;
    int wr = w >> 1, wc = w & 1;

    f4v acc[4][4] = {};

    for (int k0 = 0; k0 < D3; k0 += 64) {
        __syncthreads();
#pragma unroll
        for (int p = 0; p < 4; p++) {
            int flat = p * 256 + t;
            int r = flat >> 3, c = flat & 7;
            int csw = (c ^ (r & 7)) * 8;
            gload16(A  + (long)(m0 + r) * D3 + k0 + csw, As + flat * 8);
            gload16(Bm + (long)(n0 + r) * D3 + k0 + csw, Bs + flat * 8);
        }
        __syncthreads();
#pragma unroll
        for (int ks = 0; ks < 2; ks++) {
            s8v af[4], bf[4];
#pragma unroll
            for (int i = 0; i < 4; i++) {
                int ra = wr * 64 + i * 16 + lx;
                af[i] = *(const s8v*)(As + ra * 64 + (((ks * 4 + lh) ^ (ra & 7)) * 8));
                int rb = wc * 64 + i * 16 + lx;
                bf[i] = *(const s8v*)(Bs + rb * 64 + (((ks * 4 + lh) ^ (rb & 7)) * 8));
            }
#pragma unroll
            for (int i = 0; i < 4; i++)
#pragma unroll
                for (int j = 0; j < 4; j++)
                    acc[i][j] = __builtin_amdgcn_mfma_f32_16x16x32_bf16(
                        af[i], bf[j], acc[i][j], 0, 0, 0);
        }
    }

#pragma unroll
    for (int i = 0; i < 4; i++) {
#pragma unroll
        for (int r = 0; r < 4; r++) {
            int m = m0 + wr * 64 + i * 16 + lh * 4 + r;
#pragma unroll
            for (int j = 0; j < 4; j++) {
                int n = n0 + wc * 64 + j * 16 + lx;
                C[(long)m * ldc + n] = f2b(acc[i][j][r]);
            }
        }
    }
}

// ---------------------------------------------------------------------------
// bf16 MFMA GEMM (NT). global_load_lds staging (16B/lane): linear LDS dest,
// column-swizzled global source.
// ---------------------------------------------------------------------------
template<bool BF16OUT>
__global__ __launch_bounds__(256) void gemm_bf16_nt(
    const unsigned short* __restrict__ A, const unsigned short* __restrict__ Bm,
    void* __restrict__ Cout, const float* __restrict__ bias,
    int M, int N, int K, int lda, int ldb, int ldc)
{
    __shared__ __align__(16) unsigned short As[128 * 64];
    __shared__ __align__(16) unsigned short Bs[128 * 64];

    int t = threadIdx.x;
    int l = t & 63, w = t >> 6;
    int lx = l & 15, lh = l >> 4;
    int wr = w >> 1, wc = w & 1;
    int m0 = blockIdx.x * 128, n0 = blockIdx.y * 128;

    f4v acc[4][4] = {};

    for (int k0 = 0; k0 < K; k0 += 64) {
        __syncthreads();
#pragma unroll
        for (int p = 0; p < 4; p++) {
            int flat = p * 256 + t;
            int r = flat >> 3, c = flat & 7;
            int csw = (c ^ (r & 7)) * 8;
            gload16(A  + (long)(m0 + r) * lda + k0 + csw, As + flat * 8);
            gload16(Bm + (long)(n0 + r) * ldb + k0 + csw, Bs + flat * 8);
        }
        __syncthreads();
#pragma unroll
        for (int ks = 0; ks < 2; ks++) {
            s8v af[4], bf[4];
#pragma unroll
            for (int i = 0; i < 4; i++) {
                int ra = wr * 64 + i * 16 + lx;
                af[i] = *(const s8v*)(As + ra * 64 + (((ks * 4 + lh) ^ (ra & 7)) * 8));
                int rb = wc * 64 + i * 16 + lx;
                bf[i] = *(const s8v*)(Bs + rb * 64 + (((ks * 4 + lh) ^ (rb & 7)) * 8));
            }
#pragma unroll
            for (int i = 0; i < 4; i++)
#pragma unroll
                for (int j = 0; j < 4; j++)
                    acc[i][j] = __builtin_amdgcn_mfma_f32_16x16x32_bf16(
                        af[i], bf[j], acc[i][j], 0, 0, 0);
        }
    }

#pragma unroll
    for (int i = 0; i < 4; i++) {
#pragma unroll
        for (int r = 0; r < 4; r++) {
            int m = m0 + wr * 64 + i * 16 + lh * 4 + r;
#pragma unroll
            for (int j = 0; j < 4; j++) {
                int n = n0 + wc * 64 + j * 16 + lx;
                float v = acc[i][j][r];
                if (bias) v += bias[n];
                if (BF16OUT) ((unsigned short*)Cout)[(long)m * ldc + n] = f2b(v);
                else         ((float*)Cout)[(long)m * ldc + n] = v;
            }
        }
    }
}

// ---------------------------------------------------------------------------
// K/V conv-GEMM, z-batched. gload_lds staging; halo rows redirect their
// global source to a 16B zero region (zsrc). Bias (C' @ w^T) in bf16.
// ---------------------------------------------------------------------------
__global__ __launch_bounds__(256) void convgemm_k(
    const unsigned short* __restrict__ xvb,   // [B*S, 64] bf16
    const unsigned short* __restrict__ Weff0, // 2x [512, 640] bf16
    const unsigned short* __restrict__ bias0, // 2x [512, 512] bf16
    unsigned short* __restrict__ Cout0,       // 2x [B*S, 512] bf16
    const unsigned short* __restrict__ zsrc)  // >=16 zero bytes
{
    __shared__ __align__(16) unsigned short As[128 * 64];
    __shared__ __align__(16) unsigned short Bs[128 * 64];

    int z = blockIdx.z;
    const unsigned short* Weff = Weff0 + (long)z * DM * 640;
    const unsigned short* bias2d = bias0 + (long)z * S * DM;
    unsigned short* Cout = Cout0 + (long)z * B * S * DM;

    int t = threadIdx.x;
    int l = t & 63, w = t >> 6;
    int lx = l & 15, lh = l >> 4;
    int wr = w >> 1, wc = w & 1;
    int m0 = blockIdx.x * 128, n0 = blockIdx.y * 128;
    int b = m0 >> 9, s0 = m0 & 511;

    f4v acc[4][4] = {};

    for (int j = 0; j < 9; j++) {
        __syncthreads();
#pragma unroll
        for (int p = 0; p < 4; p++) {
            int flat = p * 256 + t;
            int r = flat >> 3, c = flat & 7;
            int csw = (c ^ (r & 7)) * 8;
            int ss = s0 + r + j - 4;
            const unsigned short* asrc = (ss >= 0 && ss < S)
                ? xvb + ((long)b * S + ss) * VD + csw : zsrc;
            gload16(asrc, As + flat * 8);
            gload16(Weff + (long)(n0 + r) * 640 + j * 64 + csw, Bs + flat * 8);
        }
        __syncthreads();
#pragma unroll
        for (int ks = 0; ks < 2; ks++) {
            s8v af[4], bf[4];
#pragma unroll
            for (int i = 0; i < 4; i++) {
                int ra = wr * 64 + i * 16 + lx;
                af[i] = *(const s8v*)(As + ra * 64 + (((ks * 4 + lh) ^ (ra & 7)) * 8));
                int rb = wc * 64 + i * 16 + lx;
                bf[i] = *(const s8v*)(Bs + rb * 64 + (((ks * 4 + lh) ^ (rb & 7)) * 8));
            }
#pragma unroll
            for (int i = 0; i < 4; i++)
#pragma unroll
                for (int jj = 0; jj < 4; jj++)
                    acc[i][jj] = __builtin_amdgcn_mfma_f32_16x16x32_bf16(
                        af[i], bf[jj], acc[i][jj], 0, 0, 0);
        }
    }

#pragma unroll
    for (int i = 0; i < 4; i++) {
#pragma unroll
        for (int r = 0; r < 4; r++) {
            int m = m0 + wr * 64 + i * 16 + lh * 4 + r;
            int s = m & 511;
#pragma unroll
            for (int jj = 0; jj < 4; jj++) {
                int n = n0 + wc * 64 + jj * 16 + lx;
                Cout[(long)m * DM + n] =
                    f2b(acc[i][jj][r] + b2f(bias2d[(long)s * DM + n]));
            }
        }
    }
}

// ---------------------------------------------------------------------------
// MFMA flash attention, no-max softmax in base-2 (log2e folded into wq):
// p = 2^pacc = e^{qk/8} exactly. K/V reg prefetch (T14); setprio (T5).
// ---------------------------------------------------------------------------
__global__ __launch_bounds__(256) void attn_mfma_k(
    const unsigned short* __restrict__ qb, const unsigned short* __restrict__ kb,
    const unsigned short* __restrict__ vb, unsigned short* __restrict__ ob)
{
    __shared__ __align__(16) unsigned short Qs[64 * 64];
    __shared__ __align__(16) unsigned short Ks[64 * 64];
    __shared__ __align__(16) unsigned short Vt[64 * 64];
    __shared__ __align__(16) unsigned short Ps[64 * 64];

    int lt = blockIdx.x, h = blockIdx.y, b = blockIdx.z;
    int t = threadIdx.x, l = t & 63, w = t >> 6, lx = l & 15, lh = l >> 4;

    const unsigned short* qg = qb + ((long)(b * L + lt * 64)) * DM + h * 64;
    const unsigned short* kg = kb + ((long)b * S) * DM + h * 64;
    const unsigned short* vg = vb + ((long)b * S) * DM + h * 64;

    // stage Q
#pragma unroll
    for (int p = 0; p < 2; p++) {
        int flat = p * 256 + t;
        int r = flat >> 3, c = flat & 7;
        s8v v = *(const s8v*)(qg + (long)r * DM + c * 8);
        *(s8v*)(Qs + r * 64 + ((c ^ (r & 7)) * 8)) = v;
    }

    int kr0 = t >> 3, kc = t & 7;          // K staging coords
    int vs = t & 63, vdq = t >> 6;         // V staging coords
    s8v k0, k1, v0, v1;

    auto loadKV = [&](int st) {
        k0 = *(const s8v*)(kg + (long)(st * 64 + kr0) * DM + kc * 8);
        k1 = *(const s8v*)(kg + (long)(st * 64 + 32 + kr0) * DM + kc * 8);
        const unsigned short* vp = vg + (long)(st * 64 + vs) * DM + vdq * 16;
        v0 = *(const s8v*)(vp);
        v1 = *(const s8v*)(vp + 8);
    };
    auto writeKV = [&]() {
        *(s8v*)(Ks + kr0 * 64 + ((kc ^ (kr0 & 7)) * 8)) = k0;
        int r2 = 32 + kr0;
        *(s8v*)(Ks + r2 * 64 + ((kc ^ (r2 & 7)) * 8)) = k1;
#pragma unroll
        for (int e = 0; e < 8; e++) {
            int d1 = vdq * 16 + e;
            Vt[d1 * 64 + (((vs >> 3) ^ (d1 & 7)) * 8) + (vs & 7)] =
                (unsigned short)v0[e];
            int d2 = vdq * 16 + 8 + e;
            Vt[d2 * 64 + (((vs >> 3) ^ (d2 & 7)) * 8) + (vs & 7)] =
                (unsigned short)v1[e];
        }
    };

    loadKV(0);
    writeKV();
    __syncthreads();

    float lrow[4] = {0.f, 0.f, 0.f, 0.f};
    f4v oacc[4] = {};

    for (int st = 0; st < S / 64; st++) {
        if (st < S / 64 - 1) loadKV(st + 1);          // prefetch next tile

        // P = Q K^T  (scale * log2e folded into Q)
        f4v pacc[4] = {};
        __builtin_amdgcn_s_setprio(1);
#pragma unroll
        for (int ks = 0; ks < 2; ks++) {
            int qr = w * 16 + lx;
            s8v a = *(const s8v*)(Qs + qr * 64 + (((ks * 4 + lh) ^ (qr & 7)) * 8));
#pragma unroll
            for (int jf = 0; jf < 4; jf++) {
                int kr = jf * 16 + lx;
                s8v bf = *(const s8v*)(Ks + kr * 64 + (((ks * 4 + lh) ^ (kr & 7)) * 8));
                pacc[jf] = __builtin_amdgcn_mfma_f32_16x16x32_bf16(a, bf, pacc[jf], 0, 0, 0);
            }
        }
        __builtin_amdgcn_s_setprio(0);

        // softmax-lite: p = 2^x (v_exp_f32), accumulate row sums, store bf16
#pragma unroll
        for (int r = 0; r < 4; r++) {
            int prow = w * 16 + lh * 4 + r;
#pragma unroll
            for (int jf = 0; jf < 4; jf++) {
                float pe = __builtin_amdgcn_exp2f(pacc[jf][r]);
                lrow[r] += pe;
                int col = jf * 16 + lx;
                Ps[prow * 64 + (((col >> 3) ^ (prow & 7)) * 8) + (col & 7)] = f2b(pe);
            }
        }
        asm volatile("s_waitcnt lgkmcnt(0)" ::: "memory");   // wave-local P vis

        // O += P V
        __builtin_amdgcn_s_setprio(1);
#pragma unroll
        for (int ks2 = 0; ks2 < 2; ks2++) {
            int pr = w * 16 + lx;
            s8v pa = *(const s8v*)(Ps + pr * 64 + (((ks2 * 4 + lh) ^ (pr & 7)) * 8));
#pragma unroll
            for (int df = 0; df < 4; df++) {
                int vr = df * 16 + lx;
                s8v vf = *(const s8v*)(Vt + vr * 64 + (((ks2 * 4 + lh) ^ (vr & 7)) * 8));
                oacc[df] = __builtin_amdgcn_mfma_f32_16x16x32_bf16(pa, vf, oacc[df], 0, 0, 0);
            }
        }
        __builtin_amdgcn_s_setprio(0);
        __syncthreads();                   // all waves done with Ks/Vt
        if (st < S / 64 - 1) {
            writeKV();                     // commit prefetched tile
            __syncthreads();
        }
    }

    // epilogue: one lane-reduce of l per row, then write O/l
    unsigned short* og = ob + ((long)(b * L + lt * 64 + w * 16)) * DM + h * 64;
#pragma unroll
    for (int r = 0; r < 4; r++) {
        float ls = lrow[r];
#pragma unroll
        for (int msk = 1; msk < 16; msk <<= 1) ls += __shfl_xor(ls, msk);
        float inv = 1.f / ls;
#pragma unroll
        for (int df = 0; df < 4; df++)
            og[(long)(lh * 4 + r) * DM + df * 16 + lx] = f2b(oacc[df][r] * inv);
    }
}

// ---------------------------------------------------------------------------
// Final fuse: out = LN( x_spatial + sigmoid(gamma) * fc_out ), bf16 inputs
// for fc_out and gamma logits. Each thread owns 2 consecutive channels.
// ---------------------------------------------------------------------------
__global__ __launch_bounds__(256) void final_k(
    const float* __restrict__ xs, const unsigned short* __restrict__ fcb,
    const unsigned short* __restrict__ gb,
    const float* __restrict__ ln_g, const float* __restrict__ ln_b,
    float* __restrict__ out)
{
    int bl = blockIdx.x;                 // b*L + l
    int b = bl >> 10, lq = bl & 1023;
    int t = threadIdx.x;
    int d0 = t * 2;
    const unsigned short* g = gb + ((long)b * S + (lq & 511)) * DM;

    __shared__ float red[2][4];

    float2 xv = *(const float2*)(xs + (long)bl * DM + d0);
    unsigned int fp = *(const unsigned int*)(fcb + (long)bl * DM + d0);
    unsigned int gp = *(const unsigned int*)(g + d0);

    float fo0 = b2f(fp & 0xffffu), fo1 = b2f(fp >> 16);
    float ga0 = 1.f / (1.f + __expf(-b2f(gp & 0xffffu)));
    float ga1 = 1.f / (1.f + __expf(-b2f(gp >> 16)));
    float r0 = xv.x + ga0 * fo0;
    float r1 = xv.y + ga1 * fo1;

    float sum = r0 + r1, sumsq = r0 * r0 + r1 * r1;
#pragma unroll
    for (int msk = 1; msk < 64; msk <<= 1) {
        sum   += __shfl_xor(sum, msk);
        sumsq += __shfl_xor(sumsq, msk);
    }
    int wave = t >> 6;
    if ((t & 63) == 0) { red[0][wave] = sum; red[1][wave] = sumsq; }
    __syncthreads();
    float tot   = red[0][0] + red[0][1] + red[0][2] + red[0][3];
    float totsq = red[1][0] + red[1][1] + red[1][2] + red[1][3];

    float mu  = tot * (1.0f / DM);
    float var = totsq * (1.0f / DM) - mu * mu;
    float inv = rsqrtf(var + 1e-5f);

    float2 lg = *(const float2*)(ln_g + d0);
    float2 lb = *(const float2*)(ln_b + d0);
    float2 o;
    o.x = (r0 - mu) * inv * lg.x + lb.x;
    o.y = (r1 - mu) * inv * lg.y + lb.y;
    *(float2*)(out + (long)bl * DM + d0) = o;
}

// ---------------------------------------------------------------------------
// Launch
// ---------------------------------------------------------------------------
extern "C" void kernel_launch(void* const* d_in, const int* in_sizes, int n_in,
                              void* d_out, int out_size, void* d_ws, size_t ws_size,
                              hipStream_t stream) {
    (void)in_sizes; (void)n_in; (void)out_size; (void)ws_size;

    const float* x_spatial  = (const float*)d_in[0];
    const float* x_velocity = (const float*)d_in[1];
    const float* w_gamma    = (const float*)d_in[2];
    const float* w3 = (const float*)d_in[3];
    const float* b3 = (const float*)d_in[4];
    const float* w5 = (const float*)d_in[5];
    const float* b5 = (const float*)d_in[6];
    const float* w7 = (const float*)d_in[7];
    const float* b7 = (const float*)d_in[8];
    const float* rel_table = (const float*)d_in[9];
    const float* dw_w = (const float*)d_in[10];
    const float* dw_b = (const float*)d_in[11];
    const float* wq   = (const float*)d_in[12];
    const float* wk   = (const float*)d_in[13];
    const float* wv   = (const float*)d_in[14];
    const float* fc_w = (const float*)d_in[15];
    const float* fc_b = (const float*)d_in[16];
    const float* ln_g = (const float*)d_in[17];
    const float* ln_b = (const float*)d_in[18];
    float* out = (float*)d_out;

    char* p = (char*)d_ws;
    auto alloc = [&](size_t bytes) {
        char* r = p;
        p += (bytes + 255) & ~(size_t)255;
        return r;
    };
    unsigned short* gamma_bf = (unsigned short*)alloc((size_t)B * S * DM * 2);
    unsigned short* fcb      = (unsigned short*)alloc((size_t)B * L * DM * 2);
    unsigned short* xs_bf   = (unsigned short*)alloc((size_t)B * L * DM * 2);
    unsigned short* xv_bf   = (unsigned short*)alloc((size_t)B * S * VD * 2);
    unsigned short* qbuf    = (unsigned short*)alloc((size_t)B * L * DM * 2);
    unsigned short* kbuf    = (unsigned short*)alloc((size_t)B * S * DM * 2);  // contiguous
    unsigned short* vbuf    = (unsigned short*)alloc((size_t)B * S * DM * 2);  //   with kbuf
    unsigned short* attn_bf = (unsigned short*)alloc((size_t)B * L * DM * 2);
    unsigned short* wq_bf   = (unsigned short*)alloc((size_t)DM * DM * 2);
    unsigned short* wk_bf   = (unsigned short*)alloc((size_t)DM * D3 * 2);     // contiguous
    unsigned short* wv_bf   = (unsigned short*)alloc((size_t)DM * D3 * 2);     //   with wk_bf
    unsigned short* fcw_bf  = (unsigned short*)alloc((size_t)DM * DM * 2);
    unsigned short* wg_bf   = (unsigned short*)alloc((size_t)DM * VD * 2);
    unsigned short* WpeT    = (unsigned short*)alloc((size_t)640 * D3 * 2);
    unsigned short* Cp      = (unsigned short*)alloc((size_t)S * D3 * 2);
    unsigned short* WkEff   = (unsigned short*)alloc((size_t)DM * 640 * 2);    // contiguous
    unsigned short* WvEff   = (unsigned short*)alloc((size_t)DM * 640 * 2);    //   with WkEff
    unsigned short* Ckb     = (unsigned short*)alloc((size_t)S * DM * 2);      // contiguous
    unsigned short* Cvb     = (unsigned short*)alloc((size_t)S * DM * 2);      //   with Ckb
    (void)WvEff; (void)Cvb;

    // 0) cast to bf16 (wq scaled by 0.125 * log2(e) for base-2 softmax)
    CastArgs ca;
    ca.src[0] = x_spatial;  ca.dst[0] = xs_bf;  ca.n[0] = B * L * DM; ca.scale[0] = 1.f;
    ca.src[1] = x_velocity; ca.dst[1] = xv_bf;  ca.n[1] = B * S * VD; ca.scale[1] = 1.f;
    ca.src[2] = wq;         ca.dst[2] = wq_bf;  ca.n[2] = DM * DM;    ca.scale[2] = 0.125f * 1.44269504089f;
    ca.src[3] = wk;         ca.dst[3] = wk_bf;  ca.n[3] = DM * D3;    ca.scale[3] = 1.f;
    ca.src[4] = wv;         ca.dst[4] = wv_bf;  ca.n[4] = DM * D3;    ca.scale[4] = 1.f;
    ca.src[5] = fc_w;       ca.dst[5] = fcw_bf; ca.n[5] = DM * DM;    ca.scale[5] = 1.f;
    ca.src[6] = w_gamma;    ca.dst[6] = wg_bf;  ca.n[6] = DM * VD;    ca.scale[6] = 1.f;
    cast7_k<<<dim3(1024, 7), 256, 0, stream>>>(ca);

    // 1) merged precompute: WpeT + C'
    prep_k<<<dim3(1152), 192, 0, stream>>>(
        w3, w5, w7, dw_w, rel_table, b3, b5, b7, dw_b, WpeT, Cp);

    // 2) unified precompute GEMM: WkEff/WvEff + Ckb/Cvb
    pre_gemm_k<<<dim3(4, 5, 4), 256, 0, stream>>>(
        wk_bf, wv_bf, WpeT, Cp, WkEff, Ckb);

    // 3) gamma logits (bf16): [4096,512] = xv_bf @ wg_bf^T, K=64
    gemm_bf16_nt<true><<<dim3(32, 4), 256, 0, stream>>>(
        xv_bf, wg_bf, gamma_bf, nullptr, B * S, DM, VD, VD, VD, DM);

    // 4) Q (bf16, pre-scaled): [8192,512], K=512
    gemm_bf16_nt<true><<<dim3(64, 4), 256, 0, stream>>>(
        xs_bf, wq_bf, qbuf, nullptr, B * L, DM, DM, DM, DM, DM);

    // 5) K/V via composed conv-GEMM (z-batched, 9 x K64 chunks)
    convgemm_k<<<dim3(32, 4, 2), 256, 0, stream>>>(
        xv_bf, WkEff, Ckb, kbuf, WkEff + 576 /* zero region */);

    // 6) attention (bf16 out)
    attn_mfma_k<<<dim3(L / 64, H, B), 256, 0, stream>>>(qbuf, kbuf, vbuf, attn_bf);

    // 7) fc (bf16 out + bias): [8192,512], K=512
    gemm_bf16_nt<true><<<dim3(64, 4), 256, 0, stream>>>(
        attn_bf, fcw_bf, fcb, fc_b, B * L, DM, DM, DM, DM, DM);

    // 8) gated residual + LayerNorm
    final_k<<<dim3(B * L), 256, 0, stream>>>(
        x_spatial, fcb, gamma_bf, ln_g, ln_b, out);
}

// Round 9
// 188.945 us; speedup vs baseline: 1.6947x; 1.1130x over previous
//
#include <hip/hip_runtime.h>
#include <hip/hip_bf16.h>

// Problem constants (fixed by the reference setup)
constexpr int B  = 8;
constexpr int L  = 1024;
constexpr int S  = 512;
constexpr int VD = 64;    // velocity dim
constexpr int DM = 512;   // d_model == spatial_dim
constexpr int D3 = 192;   // 3 * VD
constexpr int H  = 8;     // heads
constexpr int DK = 64;    // dm / H

typedef __attribute__((ext_vector_type(8))) short s8v;     // 8 bf16 (4 VGPRs)
typedef __attribute__((ext_vector_type(4))) float f4v;     // MFMA accum

__device__ inline unsigned short f2b(float f) {            // f32 -> bf16 RNE
    unsigned int u = __builtin_bit_cast(unsigned int, f);
    u += 0x7fffu + ((u >> 16) & 1u);
    return (unsigned short)(u >> 16);
}
__device__ inline float b2f(unsigned int lo16) {           // bf16 bits -> f32
    return __builtin_bit_cast(float, lo16 << 16);
}

// async global->LDS, 16B per lane. LDS dest must be wave-uniform base +
// lane*16 (linear); swizzle is applied on the GLOBAL source side (rule 21).
__device__ __forceinline__ void gload16(const void* g, void* l) {
    __builtin_amdgcn_global_load_lds(
        (const __attribute__((address_space(1))) void*)g,
        (__attribute__((address_space(3))) void*)l, 16, 0, 0);
}

// ---------------------------------------------------------------------------
// Launch 1: fused cast (7 buffers) + precompute tables.
// grid (1152, 8): y<7 -> cast task y (grid-stride); y==7 -> WpeT/Cp build.
// ---------------------------------------------------------------------------
struct CastArgs {
    const float* src[7];
    unsigned short* dst[7];
    int n[7];
    float scale[7];
};

__global__ __launch_bounds__(256) void prep_cast_k(
    CastArgs a,
    const float* __restrict__ w3, const float* __restrict__ w5,
    const float* __restrict__ w7, const float* __restrict__ dw_w,
    const float* __restrict__ rel_table, const float* __restrict__ b3,
    const float* __restrict__ b5, const float* __restrict__ b7,
    const float* __restrict__ dw_b,
    unsigned short* __restrict__ WpeT, unsigned short* __restrict__ Cp)
{
    int t = threadIdx.x;
    int y = blockIdx.y;

    if (y < 7) {                              // ---- cast part ----
        const float* s = a.src[y];
        unsigned short* d = a.dst[y];
        int n = a.n[y];
        float sc = a.scale[y];
        for (long i = (long)(blockIdx.x * 256 + t) * 4; i < n;
             i += (long)gridDim.x * 1024) {
            float4 f = *(const float4*)(s + i);
            ushort4 o;
            o.x = f2b(f.x * sc); o.y = f2b(f.y * sc);
            o.z = f2b(f.z * sc); o.w = f2b(f.w * sc);
            *(ushort4*)(d + i) = o;
        }
        return;
    }

    if (t >= 192) return;                     // ---- table part ----
    int o = t;
    float inv = 1.0f / S;

    if (blockIdx.x < 640) {                   // WpeT rows (>=576 zeroed)
        int n = blockIdx.x;
        if (n >= 576) { WpeT[n * D3 + o] = 0; return; }
        int j = n >> 6, c = n & 63, delta = j - 4;
        const float* w; int KW, P, oo;
        if (o < 64)       { w = w3; KW = 3; P = 1; oo = o; }
        else if (o < 128) { w = w5; KW = 5; P = 2; oo = o - 64; }
        else              { w = w7; KW = 7; P = 3; oo = o - 128; }
        float mu0 = dw_w[o * 3 + 0] * inv;
        float mu1 = 1.f + (dw_w[o * 3 + 1] - 1.f) * inv;
        float mu2 = dw_w[o * 3 + 2] * inv;
        float acc = 0.f;
        int k;
        k = delta + 1 + P; if (k >= 0 && k < KW) acc += mu0 * w[(oo * 64 + c) * KW + k];
        k = delta + P;     if (k >= 0 && k < KW) acc += mu1 * w[(oo * 64 + c) * KW + k];
        k = delta - 1 + P; if (k >= 0 && k < KW) acc += mu2 * w[(oo * 64 + c) * KW + k];
        WpeT[n * D3 + o] = f2b(acc);
        return;
    }

    int j = blockIdx.x - 640;                 // C'(s,o)
    float acc = 0.f;
#pragma unroll
    for (int r = 1; r < 60; r++) {
        int i = j - (r - 30);
        if (i >= 0 && i < S) acc += rel_table[r * D3 + o];
    }
    float c60 = (float)max(0, j - 29);
    float c0  = (float)max(0, (S - 30) - j);
    acc += c60 * rel_table[60 * D3 + o] + c0 * rel_table[0 * D3 + o];
    float mean_rel = acc * inv;

    float bo  = (o < 64) ? b3[o] : (o < 128) ? b5[o - 64] : b7[o - 128];
    float dw0 = dw_w[o * 3], dw1 = dw_w[o * 3 + 1], dw2 = dw_w[o * 3 + 2];
    float r29 = rel_table[29 * D3 + o], r30 = rel_table[30 * D3 + o],
          r31 = rel_table[31 * D3 + o];
    float alpha = 1.f + (dw1 - 1.f) * inv, beta = dw0 * inv, gamma = dw2 * inv;

    float cp = mean_rel + bo * alpha + (dw1 * r30 + dw_b[o] - r30) * inv;
    if (j > 0)     cp += beta * bo + dw0 * r29 * inv;
    if (j < S - 1) cp += gamma * bo + dw2 * r31 * inv;
    Cp[j * D3 + o] = f2b(cp);
}

// ---------------------------------------------------------------------------
// Launch 2: unified small-GEMM dispatch (bf16 out, no bias), grid (32,5,5):
//  z=0: WkEff = wk @ WpeT^T [512,640] K=192    z=1: WvEff likewise
//  z=2: Ckb   = Cp @ wk^T   [512,512] K=192    z=3: Cvb likewise
//  z=4: gamma = xv @ wg^T   [4096,512] K=64
// ---------------------------------------------------------------------------
__global__ __launch_bounds__(256) void pre_gemm5_k(
    const unsigned short* __restrict__ wk_bf,
    const unsigned short* __restrict__ wv_bf,
    const unsigned short* __restrict__ WpeT,
    const unsigned short* __restrict__ Cp,
    const unsigned short* __restrict__ xv_bf,
    const unsigned short* __restrict__ wg_bf,
    unsigned short* __restrict__ WEff,        // 2x [512, 640]
    unsigned short* __restrict__ Cb,          // 2x [512, 512]
    unsigned short* __restrict__ gamma_bf)    // [4096, 512]
{
    int z = blockIdx.z, mx = blockIdx.x, ny = blockIdx.y;
    const unsigned short *A, *Bm;
    unsigned short* C;
    int K, lda, ldb, ldc;
    if (z < 2) {
        if (mx >= 4) return;
        A = z ? wv_bf : wk_bf; Bm = WpeT; C = WEff + (long)z * DM * 640;
        K = D3; lda = D3; ldb = D3; ldc = 640;
    } else if (z < 4) {
        if (mx >= 4 || ny >= 4) return;
        A = Cp; Bm = (z == 2) ? wk_bf : wv_bf; C = Cb + (long)(z - 2) * S * DM;
        K = D3; lda = D3; ldb = D3; ldc = DM;
    } else {
        if (ny >= 4) return;
        A = xv_bf; Bm = wg_bf; C = gamma_bf;
        K = VD; lda = VD; ldb = VD; ldc = DM;
    }

    __shared__ __align__(16) unsigned short As[128 * 64];
    __shared__ __align__(16) unsigned short Bs[128 * 64];

    int t = threadIdx.x;
    int l = t & 63, w = t >> 6;
    int lx = l & 15, lh = l >> 4;
    int wr = w >> 1, wc = w & 1;
    int m0 = mx * 128, n0 = ny * 128;

    f4v acc[4][4] = {};

    for (int k0 = 0; k0 < K; k0 += 64) {
        __syncthreads();
#pragma unroll
        for (int p = 0; p < 4; p++) {
            int flat = p * 256 + t;
            int r = flat >> 3, c = flat & 7;
            int csw = (c ^ (r & 7)) * 8;
            gload16(A  + (long)(m0 + r) * lda + k0 + csw, As + flat * 8);
            gload16(Bm + (long)(n0 + r) * ldb + k0 + csw, Bs + flat * 8);
        }
        __syncthreads();
#pragma unroll
        for (int ks = 0; ks < 2; ks++) {
            s8v af[4], bf[4];
#pragma unroll
            for (int i = 0; i < 4; i++) {
                int ra = wr * 64 + i * 16 + lx;
                af[i] = *(const s8v*)(As + ra * 64 + (((ks * 4 + lh) ^ (ra & 7)) * 8));
                int rb = wc * 64 + i * 16 + lx;
                bf[i] = *(const s8v*)(Bs + rb * 64 + (((ks * 4 + lh) ^ (rb & 7)) * 8));
            }
#pragma unroll
            for (int i = 0; i < 4; i++)
#pragma unroll
                for (int j = 0; j < 4; j++)
                    acc[i][j] = __builtin_amdgcn_mfma_f32_16x16x32_bf16(
                        af[i], bf[j], acc[i][j], 0, 0, 0);
        }
    }

#pragma unroll
    for (int i = 0; i < 4; i++) {
#pragma unroll
        for (int r = 0; r < 4; r++) {
            int m = m0 + wr * 64 + i * 16 + lh * 4 + r;
#pragma unroll
            for (int j = 0; j < 4; j++) {
                int n = n0 + wc * 64 + j * 16 + lx;
                C[(long)m * ldc + n] = f2b(acc[i][j][r]);
            }
        }
    }
}

// ---------------------------------------------------------------------------
// Launch 3: Q projection + K/V conv-GEMM in one dispatch, grid (64,4,3):
//  z=0: Q = xs @ wq^T  [8192,512] K=512 (scale pre-folded into wq)
//  z=1,2: K/V conv-GEMM (9 x K64 taps, halo via zsrc redirect)
// ---------------------------------------------------------------------------
__global__ __launch_bounds__(256) void qconv_k(
    const unsigned short* __restrict__ xs_bf,
    const unsigned short* __restrict__ wq_bf,
    unsigned short* __restrict__ qbuf,
    const unsigned short* __restrict__ xvb,
    const unsigned short* __restrict__ Weff0,
    const unsigned short* __restrict__ bias0,
    unsigned short* __restrict__ Cout0,
    const unsigned short* __restrict__ zsrc)
{
    __shared__ __align__(16) unsigned short As[128 * 64];
    __shared__ __align__(16) unsigned short Bs[128 * 64];

    int zt = blockIdx.z;
    int t = threadIdx.x;
    int l = t & 63, w = t >> 6;
    int lx = l & 15, lh = l >> 4;
    int wr = w >> 1, wc = w & 1;

    f4v acc[4][4] = {};

    if (zt == 0) {
        // ---- Q GEMM ----
        int m0 = blockIdx.x * 128, n0 = blockIdx.y * 128;
        for (int k0 = 0; k0 < DM; k0 += 64) {
            __syncthreads();
#pragma unroll
            for (int p = 0; p < 4; p++) {
                int flat = p * 256 + t;
                int r = flat >> 3, c = flat & 7;
                int csw = (c ^ (r & 7)) * 8;
                gload16(xs_bf + (long)(m0 + r) * DM + k0 + csw, As + flat * 8);
                gload16(wq_bf + (long)(n0 + r) * DM + k0 + csw, Bs + flat * 8);
            }
            __syncthreads();
#pragma unroll
            for (int ks = 0; ks < 2; ks++) {
                s8v af[4], bf[4];
#pragma unroll
                for (int i = 0; i < 4; i++) {
                    int ra = wr * 64 + i * 16 + lx;
                    af[i] = *(const s8v*)(As + ra * 64 + (((ks * 4 + lh) ^ (ra & 7)) * 8));
                    int rb = wc * 64 + i * 16 + lx;
                    bf[i] = *(const s8v*)(Bs + rb * 64 + (((ks * 4 + lh) ^ (rb & 7)) * 8));
                }
#pragma unroll
                for (int i = 0; i < 4; i++)
#pragma unroll
                    for (int j = 0; j < 4; j++)
                        acc[i][j] = __builtin_amdgcn_mfma_f32_16x16x32_bf16(
                            af[i], bf[j], acc[i][j], 0, 0, 0);
            }
        }
#pragma unroll
        for (int i = 0; i < 4; i++) {
#pragma unroll
            for (int r = 0; r < 4; r++) {
                int m = m0 + wr * 64 + i * 16 + lh * 4 + r;
#pragma unroll
                for (int j = 0; j < 4; j++) {
                    int n = n0 + wc * 64 + j * 16 + lx;
                    qbuf[(long)m * DM + n] = f2b(acc[i][j][r]);
                }
            }
        }
        return;
    }

    // ---- conv-GEMM (z-1 = 0: K, 1: V) ----
    if (blockIdx.x >= 32) return;
    int z = zt - 1;
    const unsigned short* Weff = Weff0 + (long)z * DM * 640;
    const unsigned short* bias2d = bias0 + (long)z * S * DM;
    unsigned short* Cout = Cout0 + (long)z * B * S * DM;

    int m0 = blockIdx.x * 128, n0 = blockIdx.y * 128;
    int b = m0 >> 9, s0 = m0 & 511;

    for (int j = 0; j < 9; j++) {
        __syncthreads();
#pragma unroll
        for (int p = 0; p < 4; p++) {
            int flat = p * 256 + t;
            int r = flat >> 3, c = flat & 7;
            int csw = (c ^ (r & 7)) * 8;
            int ss = s0 + r + j - 4;
            const unsigned short* asrc = (ss >= 0 && ss < S)
                ? xvb + ((long)b * S + ss) * VD + csw : zsrc;
            gload16(asrc, As + flat * 8);
            gload16(Weff + (long)(n0 + r) * 640 + j * 64 + csw, Bs + flat * 8);
        }
        __syncthreads();
#pragma unroll
        for (int ks = 0; ks < 2; ks++) {
            s8v af[4], bf[4];
#pragma unroll
            for (int i = 0; i < 4; i++) {
                int ra = wr * 64 + i * 16 + lx;
                af[i] = *(const s8v*)(As + ra * 64 + (((ks * 4 + lh) ^ (ra & 7)) * 8));
                int rb = wc * 64 + i * 16 + lx;
                bf[i] = *(const s8v*)(Bs + rb * 64 + (((ks * 4 + lh) ^ (rb & 7)) * 8));
            }
#pragma unroll
            for (int i = 0; i < 4; i++)
#pragma unroll
                for (int jj = 0; jj < 4; jj++)
                    acc[i][jj] = __builtin_amdgcn_mfma_f32_16x16x32_bf16(
                        af[i], bf[jj], acc[i][jj], 0, 0, 0);
        }
    }

#pragma unroll
    for (int i = 0; i < 4; i++) {
#pragma unroll
        for (int r = 0; r < 4; r++) {
            int m = m0 + wr * 64 + i * 16 + lh * 4 + r;
            int s = m & 511;
#pragma unroll
            for (int jj = 0; jj < 4; jj++) {
                int n = n0 + wc * 64 + jj * 16 + lx;
                Cout[(long)m * DM + n] =
                    f2b(acc[i][jj][r] + b2f(bias2d[(long)s * DM + n]));
            }
        }
    }
}

// ---------------------------------------------------------------------------
// Launch 5: fc GEMM (bf16 out + f32 bias). Standard 128x128 NT MFMA GEMM.
// ---------------------------------------------------------------------------
__global__ __launch_bounds__(256) void gemm_fc_k(
    const unsigned short* __restrict__ A, const unsigned short* __restrict__ Bm,
    unsigned short* __restrict__ Cout, const float* __restrict__ bias)
{
    __shared__ __align__(16) unsigned short As[128 * 64];
    __shared__ __align__(16) unsigned short Bs[128 * 64];

    int t = threadIdx.x;
    int l = t & 63, w = t >> 6;
    int lx = l & 15, lh = l >> 4;
    int wr = w >> 1, wc = w & 1;
    int m0 = blockIdx.x * 128, n0 = blockIdx.y * 128;

    f4v acc[4][4] = {};

    for (int k0 = 0; k0 < DM; k0 += 64) {
        __syncthreads();
#pragma unroll
        for (int p = 0; p < 4; p++) {
            int flat = p * 256 + t;
            int r = flat >> 3, c = flat & 7;
            int csw = (c ^ (r & 7)) * 8;
            gload16(A  + (long)(m0 + r) * DM + k0 + csw, As + flat * 8);
            gload16(Bm + (long)(n0 + r) * DM + k0 + csw, Bs + flat * 8);
        }
        __syncthreads();
#pragma unroll
        for (int ks = 0; ks < 2; ks++) {
            s8v af[4], bf[4];
#pragma unroll
            for (int i = 0; i < 4; i++) {
                int ra = wr * 64 + i * 16 + lx;
                af[i] = *(const s8v*)(As + ra * 64 + (((ks * 4 + lh) ^ (ra & 7)) * 8));
                int rb = wc * 64 + i * 16 + lx;
                bf[i] = *(const s8v*)(Bs + rb * 64 + (((ks * 4 + lh) ^ (rb & 7)) * 8));
            }
#pragma unroll
            for (int i = 0; i < 4; i++)
#pragma unroll
                for (int j = 0; j < 4; j++)
                    acc[i][j] = __builtin_amdgcn_mfma_f32_16x16x32_bf16(
                        af[i], bf[j], acc[i][j], 0, 0, 0);
        }
    }

#pragma unroll
    for (int i = 0; i < 4; i++) {
#pragma unroll
        for (int r = 0; r < 4; r++) {
            int m = m0 + wr * 64 + i * 16 + lh * 4 + r;
#pragma unroll
            for (int j = 0; j < 4; j++) {
                int n = n0 + wc * 64 + j * 16 + lx;
                Cout[(long)m * DM + n] = f2b(acc[i][j][r] + bias[n]);
            }
        }
    }
}

// ---------------------------------------------------------------------------
// Launch 4: MFMA flash attention, no-max softmax in base-2 (log2e folded
// into wq): p = 2^pacc = e^{qk/8} exactly. K/V reg prefetch (T14);
// setprio (T5).
// ---------------------------------------------------------------------------
__global__ __launch_bounds__(256) void attn_mfma_k(
    const unsigned short* __restrict__ qb, const unsigned short* __restrict__ kb,
    const unsigned short* __restrict__ vb, unsigned short* __restrict__ ob)
{
    __shared__ __align__(16) unsigned short Qs[64 * 64];
    __shared__ __align__(16) unsigned short Ks[64 * 64];
    __shared__ __align__(16) unsigned short Vt[64 * 64];
    __shared__ __align__(16) unsigned short Ps[64 * 64];

    int lt = blockIdx.x, h = blockIdx.y, b = blockIdx.z;
    int t = threadIdx.x, l = t & 63, w = t >> 6, lx = l & 15, lh = l >> 4;

    const unsigned short* qg = qb + ((long)(b * L + lt * 64)) * DM + h * 64;
    const unsigned short* kg = kb + ((long)b * S) * DM + h * 64;
    const unsigned short* vg = vb + ((long)b * S) * DM + h * 64;

    // stage Q
#pragma unroll
    for (int p = 0; p < 2; p++) {
        int flat = p * 256 + t;
        int r = flat >> 3, c = flat & 7;
        s8v v = *(const s8v*)(qg + (long)r * DM + c * 8);
        *(s8v*)(Qs + r * 64 + ((c ^ (r & 7)) * 8)) = v;
    }

    int kr0 = t >> 3, kc = t & 7;          // K staging coords
    int vs = t & 63, vdq = t >> 6;         // V staging coords
    s8v k0, k1, v0, v1;

    auto loadKV = [&](int st) {
        k0 = *(const s8v*)(kg + (long)(st * 64 + kr0) * DM + kc * 8);
        k1 = *(const s8v*)(kg + (long)(st * 64 + 32 + kr0) * DM + kc * 8);
        const unsigned short* vp = vg + (long)(st * 64 + vs) * DM + vdq * 16;
        v0 = *(const s8v*)(vp);
        v1 = *(const s8v*)(vp + 8);
    };
    auto writeKV = [&]() {
        *(s8v*)(Ks + kr0 * 64 + ((kc ^ (kr0 & 7)) * 8)) = k0;
        int r2 = 32 + kr0;
        *(s8v*)(Ks + r2 * 64 + ((kc ^ (r2 & 7)) * 8)) = k1;
#pragma unroll
        for (int e = 0; e < 8; e++) {
            int d1 = vdq * 16 + e;
            Vt[d1 * 64 + (((vs >> 3) ^ (d1 & 7)) * 8) + (vs & 7)] =
                (unsigned short)v0[e];
            int d2 = vdq * 16 + 8 + e;
            Vt[d2 * 64 + (((vs >> 3) ^ (d2 & 7)) * 8) + (vs & 7)] =
                (unsigned short)v1[e];
        }
    };

    loadKV(0);
    writeKV();
    __syncthreads();

    float lrow[4] = {0.f, 0.f, 0.f, 0.f};
    f4v oacc[4] = {};

    for (int st = 0; st < S / 64; st++) {
        if (st < S / 64 - 1) loadKV(st + 1);          // prefetch next tile

        // P = Q K^T  (scale * log2e folded into Q)
        f4v pacc[4] = {};
        __builtin_amdgcn_s_setprio(1);
#pragma unroll
        for (int ks = 0; ks < 2; ks++) {
            int qr = w * 16 + lx;
            s8v a = *(const s8v*)(Qs + qr * 64 + (((ks * 4 + lh) ^ (qr & 7)) * 8));
#pragma unroll
            for (int jf = 0; jf < 4; jf++) {
                int kr = jf * 16 + lx;
                s8v bf = *(const s8v*)(Ks + kr * 64 + (((ks * 4 + lh) ^ (kr & 7)) * 8));
                pacc[jf] = __builtin_amdgcn_mfma_f32_16x16x32_bf16(a, bf, pacc[jf], 0, 0, 0);
            }
        }
        __builtin_amdgcn_s_setprio(0);

        // softmax-lite: p = 2^x (v_exp_f32), accumulate row sums, store bf16
#pragma unroll
        for (int r = 0; r < 4; r++) {
            int prow = w * 16 + lh * 4 + r;
#pragma unroll
            for (int jf = 0; jf < 4; jf++) {
                float pe = __builtin_amdgcn_exp2f(pacc[jf][r]);
                lrow[r] += pe;
                int col = jf * 16 + lx;
                Ps[prow * 64 + (((col >> 3) ^ (prow & 7)) * 8) + (col & 7)] = f2b(pe);
            }
        }
        asm volatile("s_waitcnt lgkmcnt(0)" ::: "memory");   // wave-local P vis

        // O += P V
        __builtin_amdgcn_s_setprio(1);
#pragma unroll
        for (int ks2 = 0; ks2 < 2; ks2++) {
            int pr = w * 16 + lx;
            s8v pa = *(const s8v*)(Ps + pr * 64 + (((ks2 * 4 + lh) ^ (pr & 7)) * 8));
#pragma unroll
            for (int df = 0; df < 4; df++) {
                int vr = df * 16 + lx;
                s8v vf = *(const s8v*)(Vt + vr * 64 + (((ks2 * 4 + lh) ^ (vr & 7)) * 8));
                oacc[df] = __builtin_amdgcn_mfma_f32_16x16x32_bf16(pa, vf, oacc[df], 0, 0, 0);
            }
        }
        __builtin_amdgcn_s_setprio(0);
        __syncthreads();                   // all waves done with Ks/Vt
        if (st < S / 64 - 1) {
            writeKV();                     // commit prefetched tile
            __syncthreads();
        }
    }

    // epilogue: one lane-reduce of l per row, then write O/l
    unsigned short* og = ob + ((long)(b * L + lt * 64 + w * 16)) * DM + h * 64;
#pragma unroll
    for (int r = 0; r < 4; r++) {
        float ls = lrow[r];
#pragma unroll
        for (int msk = 1; msk < 16; msk <<= 1) ls += __shfl_xor(ls, msk);
        float inv = 1.f / ls;
#pragma unroll
        for (int df = 0; df < 4; df++)
            og[(long)(lh * 4 + r) * DM + df * 16 + lx] = f2b(oacc[df][r] * inv);
    }
}

// ---------------------------------------------------------------------------
// Launch 6: out = LN( x_spatial + sigmoid(gamma) * fc_out ), bf16 fc/gamma.
// ---------------------------------------------------------------------------
__global__ __launch_bounds__(256) void final_k(
    const float* __restrict__ xs, const unsigned short* __restrict__ fcb,
    const unsigned short* __restrict__ gb,
    const float* __restrict__ ln_g, const float* __restrict__ ln_b,
    float* __restrict__ out)
{
    int bl = blockIdx.x;                 // b*L + l
    int b = bl >> 10, lq = bl & 1023;
    int t = threadIdx.x;
    int d0 = t * 2;
    const unsigned short* g = gb + ((long)b * S + (lq & 511)) * DM;

    __shared__ float red[2][4];

    float2 xv = *(const float2*)(xs + (long)bl * DM + d0);
    unsigned int fp = *(const unsigned int*)(fcb + (long)bl * DM + d0);
    unsigned int gp = *(const unsigned int*)(g + d0);

    float fo0 = b2f(fp & 0xffffu), fo1 = b2f(fp >> 16);
    float ga0 = 1.f / (1.f + __expf(-b2f(gp & 0xffffu)));
    float ga1 = 1.f / (1.f + __expf(-b2f(gp >> 16)));
    float r0 = xv.x + ga0 * fo0;
    float r1 = xv.y + ga1 * fo1;

    float sum = r0 + r1, sumsq = r0 * r0 + r1 * r1;
#pragma unroll
    for (int msk = 1; msk < 64; msk <<= 1) {
        sum   += __shfl_xor(sum, msk);
        sumsq += __shfl_xor(sumsq, msk);
    }
    int wave = t >> 6;
    if ((t & 63) == 0) { red[0][wave] = sum; red[1][wave] = sumsq; }
    __syncthreads();
    float tot   = red[0][0] + red[0][1] + red[0][2] + red[0][3];
    float totsq = red[1][0] + red[1][1] + red[1][2] + red[1][3];

    float mu  = tot * (1.0f / DM);
    float var = totsq * (1.0f / DM) - mu * mu;
    float inv = rsqrtf(var + 1e-5f);

    float2 lg = *(const float2*)(ln_g + d0);
    float2 lb = *(const float2*)(ln_b + d0);
    float2 o;
    o.x = (r0 - mu) * inv * lg.x + lb.x;
    o.y = (r1 - mu) * inv * lg.y + lb.y;
    *(float2*)(out + (long)bl * DM + d0) = o;
}

// ---------------------------------------------------------------------------
// Launch
// ---------------------------------------------------------------------------
extern "C" void kernel_launch(void* const* d_in, const int* in_sizes, int n_in,
                              void* d_out, int out_size, void* d_ws, size_t ws_size,
                              hipStream_t stream) {
    (void)in_sizes; (void)n_in; (void)out_size; (void)ws_size;

    const float* x_spatial  = (const float*)d_in[0];
    const float* x_velocity = (const float*)d_in[1];
    const float* w_gamma    = (const float*)d_in[2];
    const float* w3 = (const float*)d_in[3];
    const float* b3 = (const float*)d_in[4];
    const float* w5 = (const float*)d_in[5];
    const float* b5 = (const float*)d_in[6];
    const float* w7 = (const float*)d_in[7];
    const float* b7 = (const float*)d_in[8];
    const float* rel_table = (const float*)d_in[9];
    const float* dw_w = (const float*)d_in[10];
    const float* dw_b = (const float*)d_in[11];
    const float* wq   = (const float*)d_in[12];
    const float* wk   = (const float*)d_in[13];
    const float* wv   = (const float*)d_in[14];
    const float* fc_w = (const float*)d_in[15];
    const float* fc_b = (const float*)d_in[16];
    const float* ln_g = (const float*)d_in[17];
    const float* ln_b = (const float*)d_in[18];
    float* out = (float*)d_out;

    char* p = (char*)d_ws;
    auto alloc = [&](size_t bytes) {
        char* r = p;
        p += (bytes + 255) & ~(size_t)255;
        return r;
    };
    unsigned short* gamma_bf = (unsigned short*)alloc((size_t)B * S * DM * 2);
    unsigned short* fcb      = (unsigned short*)alloc((size_t)B * L * DM * 2);
    unsigned short* xs_bf   = (unsigned short*)alloc((size_t)B * L * DM * 2);
    unsigned short* xv_bf   = (unsigned short*)alloc((size_t)B * S * VD * 2);
    unsigned short* qbuf    = (unsigned short*)alloc((size_t)B * L * DM * 2);
    unsigned short* kbuf    = (unsigned short*)alloc((size_t)B * S * DM * 2);  // contiguous
    unsigned short* vbuf    = (unsigned short*)alloc((size_t)B * S * DM * 2);  //   with kbuf
    unsigned short* attn_bf = (unsigned short*)alloc((size_t)B * L * DM * 2);
    unsigned short* wq_bf   = (unsigned short*)alloc((size_t)DM * DM * 2);
    unsigned short* wk_bf   = (unsigned short*)alloc((size_t)DM * D3 * 2);     // contiguous
    unsigned short* wv_bf   = (unsigned short*)alloc((size_t)DM * D3 * 2);     //   with wk_bf
    unsigned short* fcw_bf  = (unsigned short*)alloc((size_t)DM * DM * 2);
    unsigned short* wg_bf   = (unsigned short*)alloc((size_t)DM * VD * 2);
    unsigned short* WpeT    = (unsigned short*)alloc((size_t)640 * D3 * 2);
    unsigned short* Cp      = (unsigned short*)alloc((size_t)S * D3 * 2);
    unsigned short* WkEff   = (unsigned short*)alloc((size_t)DM * 640 * 2);    // contiguous
    unsigned short* WvEff   = (unsigned short*)alloc((size_t)DM * 640 * 2);    //   with WkEff
    unsigned short* Ckb     = (unsigned short*)alloc((size_t)S * DM * 2);      // contiguous
    unsigned short* Cvb     = (unsigned short*)alloc((size_t)S * DM * 2);      //   with Ckb
    (void)wv_bf; (void)WvEff; (void)Cvb;

    // 1) cast to bf16 (wq scaled by 0.125*log2e for base-2 softmax) + tables
    CastArgs ca;
    ca.src[0] = x_spatial;  ca.dst[0] = xs_bf;  ca.n[0] = B * L * DM; ca.scale[0] = 1.f;
    ca.src[1] = x_velocity; ca.dst[1] = xv_bf;  ca.n[1] = B * S * VD; ca.scale[1] = 1.f;
    ca.src[2] = wq;         ca.dst[2] = wq_bf;  ca.n[2] = DM * DM;    ca.scale[2] = 0.125f * 1.44269504089f;
    ca.src[3] = wk;         ca.dst[3] = wk_bf;  ca.n[3] = DM * D3;    ca.scale[3] = 1.f;
    ca.src[4] = wv;         ca.dst[4] = wv_bf;  ca.n[4] = DM * D3;    ca.scale[4] = 1.f;
    ca.src[5] = fc_w;       ca.dst[5] = fcw_bf; ca.n[5] = DM * DM;    ca.scale[5] = 1.f;
    ca.src[6] = w_gamma;    ca.dst[6] = wg_bf;  ca.n[6] = DM * VD;    ca.scale[6] = 1.f;
    prep_cast_k<<<dim3(1152, 8), 256, 0, stream>>>(
        ca, w3, w5, w7, dw_w, rel_table, b3, b5, b7, dw_b, WpeT, Cp);

    // 2) all small GEMMs in one dispatch: WkEff/WvEff + Ckb/Cvb + gamma
    pre_gemm5_k<<<dim3(32, 5, 5), 256, 0, stream>>>(
        wk_bf, wv_bf, WpeT, Cp, xv_bf, wg_bf, WkEff, Ckb, gamma_bf);

    // 3) Q projection + K/V conv-GEMM in one dispatch
    qconv_k<<<dim3(64, 4, 3), 256, 0, stream>>>(
        xs_bf, wq_bf, qbuf, xv_bf, WkEff, Ckb, kbuf,
        WkEff + 576 /* zero region */);

    // 4) attention (bf16 out)
    attn_mfma_k<<<dim3(L / 64, H, B), 256, 0, stream>>>(qbuf, kbuf, vbuf, attn_bf);

    // 5) fc (bf16 out + bias)
    gemm_fc_k<<<dim3(64, 4), 256, 0, stream>>>(attn_bf, fcw_bf, fcb, fc_b);

    // 6) gated residual + LayerNorm
    final_k<<<dim3(B * L), 256, 0, stream>>>(
        x_spatial, fcb, gamma_bf, ln_g, ln_b, out);
}